// Round 5
// baseline (221.023 us; speedup 1.0000x reference)
//
#include <hip/hip_runtime.h>
#include <stdint.h>

// Problem: B=8, L=2048, D=512, H=8, P=4, C=64.  M = B*L = 16384.
#define PSZF (16384 * 96)   // elements per offaw partial buffer (split-K half)

using short8  = __attribute__((ext_vector_type(8))) short;
using floatx4 = __attribute__((ext_vector_type(4))) float;

__device__ __forceinline__ unsigned short f2bf(float f) {  // RNE
  union { float f; unsigned u; } v; v.f = f;
  unsigned r = v.u + 0x7fffu + ((v.u >> 16) & 1u);
  return (unsigned short)(r >> 16);
}
__device__ __forceinline__ float bf2f(unsigned short u) {
  union { unsigned u; float f; } v; v.u = ((unsigned)u) << 16; return v.f;
}

__device__ __forceinline__ void load_lds16(const void* g, void* l) {
  __builtin_amdgcn_global_load_lds(
      (const __attribute__((address_space(1))) unsigned int*)g,
      (__attribute__((address_space(3))) unsigned int*)l, 16, 0, 0);
}

__device__ __forceinline__ void store_val(float* p, float v) { *p = v; }
__device__ __forceinline__ void store_val(unsigned short* p, float v) { *p = f2bf(v); }

// ---------------- K0: weight prep only (value conv is folded into gemm1) ---------
// [0,262144): W_v^T bf16   [..+262144): W_out^T bf16
// [..+49152): Bhi/Blo split-bf16 of [W_off|W_aw]^T (layout [96][512])   [..+96): bcat
__global__ __launch_bounds__(256) void prep_w(const float* __restrict__ W_v,
                                              const float* __restrict__ W_out,
                                              const float* __restrict__ Woff,
                                              const float* __restrict__ Waw,
                                              const float* __restrict__ boff,
                                              const float* __restrict__ baw,
                                              unsigned short* __restrict__ Wv_t,
                                              unsigned short* __restrict__ Wo_t,
                                              unsigned short* __restrict__ Bhi,
                                              unsigned short* __restrict__ Blo,
                                              float* __restrict__ bcat) {
  int idx = blockIdx.x * 256 + threadIdx.x;
  if (idx < 262144) {
    int n = idx >> 9, k = idx & 511;
    Wv_t[idx] = f2bf(W_v[(k << 9) + n]);
    return;
  }
  int t = idx - 262144;
  if (t < 262144) {
    int n = t >> 9, k = t & 511;
    Wo_t[t] = f2bf(W_out[(k << 9) + n]);
    return;
  }
  t -= 262144;
  if (t < 49152) {
    int n = t >> 9, k = t & 511;
    float w = (n < 64) ? Woff[(k << 6) + n] : Waw[(k << 5) + (n - 64)];
    unsigned short hi = f2bf(w);
    Bhi[t] = hi;
    Blo[t] = f2bf(w - bf2f(hi));
    return;
  }
  t -= 49152;
  if (t < 96) bcat[t] = (t < 64) ? boff[t] : baw[t - 64];
}

// ---------------- 64x64-tile bf16 MFMA GEMM body (bf16 A via global_load_lds) -----
// 4 waves as 2x2 of 32x32, BK=32, 16x16x32 MFMA.  Small tile -> 2048 blocks ->
// ~8 blocks/CU: latency hiding via TLP (round-4 counters: 80% stall at 4 blocks/CU).
template <typename OutT>
__device__ __forceinline__ void gemm64_body(unsigned short* lA, unsigned short* lB,
                                            const unsigned short* __restrict__ A,
                                            const unsigned short* __restrict__ Bt,
                                            const float* __restrict__ bias,
                                            OutT* __restrict__ C, int bx, int by) {
  int tid  = threadIdx.x;
  int lane = tid & 63, wv = tid >> 6;
  int wm = wv & 1, wn = wv >> 1;
  int lrow = lane & 15, quad = lane >> 4;
  int rowBlk = by * 64, colBlk = bx * 64;
  const unsigned short* Ab = A + (size_t)rowBlk * 512;
  const unsigned short* Bb = Bt + (size_t)colBlk * 512;
  int r0 = tid >> 2, c0 = (tid & 3) << 3;

  floatx4 acc[2][2];
#pragma unroll
  for (int i = 0; i < 2; i++)
#pragma unroll
    for (int j = 0; j < 2; j++) acc[i][j] = (floatx4){0.f, 0.f, 0.f, 0.f};

  for (int k0 = 0; k0 < 512; k0 += 32) {
    load_lds16(Ab + (size_t)r0 * 512 + k0 + c0, lA + tid * 8);
    load_lds16(Bb + (size_t)r0 * 512 + k0 + c0, lB + tid * 8);
    __syncthreads();
    short8 a[2], b[2];
#pragma unroll
    for (int mi = 0; mi < 2; mi++)
      a[mi] = *(const short8*)&lA[(wm * 32 + mi * 16 + lrow) * 32 + quad * 8];
#pragma unroll
    for (int ni = 0; ni < 2; ni++)
      b[ni] = *(const short8*)&lB[(wn * 32 + ni * 16 + lrow) * 32 + quad * 8];
#pragma unroll
    for (int mi = 0; mi < 2; mi++)
#pragma unroll
      for (int ni = 0; ni < 2; ni++)
        acc[mi][ni] = __builtin_amdgcn_mfma_f32_16x16x32_bf16(a[mi], b[ni], acc[mi][ni], 0, 0, 0);
    __syncthreads();
  }

  // C/D layout: col = lane&15, row = quad*4 + reg   [verified m89/m91]
#pragma unroll
  for (int ni = 0; ni < 2; ni++) {
    int col = colBlk + wn * 32 + ni * 16 + lrow;
    float bv = bias[col];
#pragma unroll
    for (int mi = 0; mi < 2; mi++) {
      int row = rowBlk + wm * 32 + mi * 16 + quad * 4;
#pragma unroll
      for (int r = 0; r < 4; r++)
        store_val(&C[(size_t)(row + r) * 512 + col], acc[mi][ni][r] + bv);
    }
  }
}

// ---------------- gemm1 body: fp32 A read + in-register RNE->bf16 during staging ---
// Deletes the separate value->bf16 pass (48 MB HBM + one serial launch).
__device__ __forceinline__ void gemm1_body(unsigned short* lA, unsigned short* lB,
                                           const float* __restrict__ A,
                                           const unsigned short* __restrict__ Bt,
                                           const float* __restrict__ bias,
                                           unsigned short* __restrict__ C,
                                           int bx, int by) {
  int tid  = threadIdx.x;
  int lane = tid & 63, wv = tid >> 6;
  int wm = wv & 1, wn = wv >> 1;
  int lrow = lane & 15, quad = lane >> 4;
  int rowBlk = by * 64, colBlk = bx * 64;
  const unsigned short* Bb = Bt + (size_t)colBlk * 512;
  int r0 = tid >> 2, c0 = (tid & 3) << 3;
  const float* ap = A + (size_t)(rowBlk + r0) * 512 + c0;

  floatx4 acc[2][2];
#pragma unroll
  for (int i = 0; i < 2; i++)
#pragma unroll
    for (int j = 0; j < 2; j++) acc[i][j] = (floatx4){0.f, 0.f, 0.f, 0.f};

  for (int k0 = 0; k0 < 512; k0 += 32) {
    float4 v0 = *(const float4*)(ap + k0);
    float4 v1 = *(const float4*)(ap + k0 + 4);
    float vv[8] = {v0.x, v0.y, v0.z, v0.w, v1.x, v1.y, v1.z, v1.w};
    short8 h8;
#pragma unroll
    for (int e = 0; e < 8; e++) h8[e] = (short)f2bf(vv[e]);
    *(short8*)&lA[tid * 8] = h8;
    load_lds16(Bb + (size_t)r0 * 512 + k0 + c0, lB + tid * 8);
    __syncthreads();
    short8 a[2], b[2];
#pragma unroll
    for (int mi = 0; mi < 2; mi++)
      a[mi] = *(const short8*)&lA[(wm * 32 + mi * 16 + lrow) * 32 + quad * 8];
#pragma unroll
    for (int ni = 0; ni < 2; ni++)
      b[ni] = *(const short8*)&lB[(wn * 32 + ni * 16 + lrow) * 32 + quad * 8];
#pragma unroll
    for (int mi = 0; mi < 2; mi++)
#pragma unroll
      for (int ni = 0; ni < 2; ni++)
        acc[mi][ni] = __builtin_amdgcn_mfma_f32_16x16x32_bf16(a[mi], b[ni], acc[mi][ni], 0, 0, 0);
    __syncthreads();
  }

#pragma unroll
  for (int ni = 0; ni < 2; ni++) {
    int col = colBlk + wn * 32 + ni * 16 + lrow;
    float bv = bias[col];
#pragma unroll
    for (int mi = 0; mi < 2; mi++) {
      int row = rowBlk + wm * 32 + mi * 16 + quad * 4;
#pragma unroll
      for (int r = 0; r < 4; r++)
        C[(size_t)(row + r) * 512 + col] = f2bf(acc[mi][ni][r] + bv);
    }
  }
}

// ---------------- offaw body: split-bf16 3-product MFMA (unchanged from round 4) ---
__device__ __forceinline__ void offaw_body(unsigned char* smem,
                                           const float* __restrict__ Q,
                                           const unsigned short* __restrict__ Bhi,
                                           const unsigned short* __restrict__ Blo,
                                           const float* __restrict__ bcat,
                                           float* __restrict__ P, int bid) {
  unsigned short* lAhi = (unsigned short*)smem;            // 64*32 = 4 KB
  unsigned short* lAlo = (unsigned short*)(smem + 4096);   // 4 KB
  unsigned short* lBhi = (unsigned short*)(smem + 8192);   // 96*32 = 6 KB
  unsigned short* lBlo = (unsigned short*)(smem + 14336);  // 6 KB
  int khalf = bid >> 8, row0 = (bid & 255) * 64, kbase = khalf << 8;
  int tid = threadIdx.x, lane = tid & 63, wv = tid >> 6;
  int wm = wv & 1, wn = wv >> 1, lrow = lane & 15, quad = lane >> 4;

  int ar = tid >> 2, ac = (tid & 3) << 3;
  const float* qp = Q + (size_t)(row0 + ar) * 512 + kbase + ac;

  floatx4 acc[2][3];
#pragma unroll
  for (int i = 0; i < 2; i++)
#pragma unroll
    for (int j = 0; j < 3; j++) acc[i][j] = (floatx4){0.f, 0.f, 0.f, 0.f};

  for (int k0 = 0; k0 < 256; k0 += 32) {
    float4 v0 = *(const float4*)(qp + k0);
    float4 v1 = *(const float4*)(qp + k0 + 4);
    float vv[8] = {v0.x, v0.y, v0.z, v0.w, v1.x, v1.y, v1.z, v1.w};
    short8 h8, l8;
#pragma unroll
    for (int e = 0; e < 8; e++) {
      union { float f; unsigned u; } t; t.f = vv[e];
      unsigned r = t.u + 0x7fffu + ((t.u >> 16) & 1u);
      h8[e] = (short)(r >> 16);
      union { unsigned u; float f; } hf; hf.u = r & 0xffff0000u;
      union { float f; unsigned u; } rb; rb.f = vv[e] - hf.f;
      l8[e] = (short)(rb.u >> 16);
    }
    *(short8*)&lAhi[tid * 8] = h8;
    *(short8*)&lAlo[tid * 8] = l8;
#pragma unroll
    for (int j = 0; j < 3; j++) {
      int widx = wv + (j << 2);                        // 0..11, wave-uniform
      const unsigned short* src = (widx < 6) ? Bhi : Blo;
      unsigned short* dst = (widx < 6) ? lBhi : lBlo;
      int c = (((widx < 6) ? widx : widx - 6) << 6) + lane;  // 0..383
      int n = c >> 2, cc = (c & 3) << 3;
      load_lds16(src + (size_t)n * 512 + kbase + k0 + cc, dst + c * 8);
    }
    __syncthreads();

    short8 ah[2], al[2], bh[3], bl[3];
#pragma unroll
    for (int mi = 0; mi < 2; mi++) {
      int r = (wm * 32 + mi * 16 + lrow) * 32 + quad * 8;
      ah[mi] = *(const short8*)&lAhi[r];
      al[mi] = *(const short8*)&lAlo[r];
    }
#pragma unroll
    for (int ni = 0; ni < 3; ni++) {
      int r = (wn * 48 + ni * 16 + lrow) * 32 + quad * 8;
      bh[ni] = *(const short8*)&lBhi[r];
      bl[ni] = *(const short8*)&lBlo[r];
    }
#pragma unroll
    for (int mi = 0; mi < 2; mi++)
#pragma unroll
      for (int ni = 0; ni < 3; ni++) {
        acc[mi][ni] = __builtin_amdgcn_mfma_f32_16x16x32_bf16(ah[mi], bh[ni], acc[mi][ni], 0, 0, 0);
        acc[mi][ni] = __builtin_amdgcn_mfma_f32_16x16x32_bf16(ah[mi], bl[ni], acc[mi][ni], 0, 0, 0);
        acc[mi][ni] = __builtin_amdgcn_mfma_f32_16x16x32_bf16(al[mi], bh[ni], acc[mi][ni], 0, 0, 0);
      }
    __syncthreads();
  }

  float* out = P + (size_t)khalf * PSZF;
#pragma unroll
  for (int ni = 0; ni < 3; ni++) {
    int col = wn * 48 + ni * 16 + lrow;
    float bv = (khalf == 0) ? bcat[col] : 0.0f;
#pragma unroll
    for (int mi = 0; mi < 2; mi++) {
      int row = row0 + wm * 32 + mi * 16 + quad * 4;
#pragma unroll
      for (int r = 0; r < 4; r++)
        out[(size_t)(row + r) * 96 + col] = acc[mi][ni][r] + bv;
    }
  }
}

// ---------------- K1: gemm1 (2048 blocks) + offaw (512 blocks) -------------------
__global__ __launch_bounds__(256) void mega_k1(const float* __restrict__ value,
                                               const unsigned short* __restrict__ Wv_t,
                                               const float* __restrict__ b_v,
                                               unsigned short* __restrict__ v_bf,
                                               const float* __restrict__ query,
                                               const unsigned short* __restrict__ Bhi,
                                               const unsigned short* __restrict__ Blo,
                                               const float* __restrict__ bcat,
                                               float* __restrict__ offP) {
  __shared__ __align__(16) unsigned char smem[20480];
  int bx = blockIdx.x;
  if (bx < 2048)
    gemm1_body((unsigned short*)smem, (unsigned short*)(smem + 4096),
               value, Wv_t, b_v, v_bf, bx & 7, bx >> 3);
  else
    offaw_body(smem, query, Bhi, Blo, bcat, offP, bx - 2048);
}

// ---------------- K3: out = attn @ W_out + b_out  (64x64 tiles, 2048 blocks) ------
__global__ __launch_bounds__(256) void gemm2_k(const unsigned short* __restrict__ A,
                                               const unsigned short* __restrict__ Bt,
                                               const float* __restrict__ bias,
                                               float* __restrict__ C) {
  __shared__ __align__(16) unsigned short lA[2048];
  __shared__ __align__(16) unsigned short lB[2048];
  gemm64_body<float>(lA, lB, A, Bt, bias, C, blockIdx.x & 7, blockIdx.x >> 3);
}

// ---------------- K2: fused softmax + 1-D grid-sample gather ----------------------
// 8 rows per block; all 256 threads active in setup (thread = (row, h*4+p)).
// iy0 == 0 always (iy in [0,0.5]) so ywt = 1 - 0.5*loc_y.
__global__ __launch_bounds__(256) void sample_kernel(const float* __restrict__ P,
                                                     const unsigned short* __restrict__ v,
                                                     unsigned short* __restrict__ attn) {
  int tid = threadIdx.x;
  int rr = tid >> 5, hp = tid & 31;
  int row = blockIdx.x * 8 + rr;
  int l = row & 2047;
  __shared__ float s_w0[8][32], s_w1[8][32];
  __shared__ int s_i0[8][32], s_i1[8][32];
  {
    int base = row * 96;
    float lg = P[base + 64 + hp] + P[PSZF + base + 64 + hp];
    float mx = fmaxf(lg, __shfl_xor(lg, 1));
    mx = fmaxf(mx, __shfl_xor(mx, 2));
    float e = __expf(lg - mx);
    float s = e + __shfl_xor(e, 1);
    s = s + __shfl_xor(s, 2);
    float aw = e / s;

    float ox = P[base + 2 * hp] + P[PSZF + base + 2 * hp];
    float oy = P[base + 2 * hp + 1] + P[PSZF + base + 2 * hp + 1];
    float refy = (float)l * (1.0f / 2047.0f);
    float lx = fminf(fmaxf(ox, 0.0f), 1.0f);
    float ly = fminf(fmaxf(oy + refy, 0.0f), 1.0f);
    float ix = ((lx + 1.0f) * 2048.0f - 1.0f) * 0.5f;
    float ywt = 1.0f - ly * 0.5f;
    float ix0 = floorf(ix);
    float fx = ix - ix0;
    int i0 = (int)ix0;
    int i1 = i0 + 1;
    s_w0[rr][hp] = aw * ywt * (1.0f - fx);
    s_w1[rr][hp] = (i1 < 2048) ? (aw * ywt * fx) : 0.0f;
    s_i0[rr][hp] = i0;
    s_i1[rr][hp] = (i1 < 2048) ? i1 : 2047;
  }
  __syncthreads();

  int b = (blockIdx.x * 8) >> 11;                 // 8 rows never cross a batch
  int h = tid >> 5, c = (tid & 31) << 1;
  const unsigned short* vhc = v + ((size_t)(b << 11)) * 512 + h * 64 + c;
#pragma unroll
  for (int r8 = 0; r8 < 8; r8++) {
    int row2 = blockIdx.x * 8 + r8;
    float ax = 0.0f, ay = 0.0f;
#pragma unroll
    for (int p = 0; p < 4; p++) {
      int t = (h << 2) + p;
      unsigned g0 = *(const unsigned*)(vhc + ((size_t)s_i0[r8][t] << 9));
      unsigned g1 = *(const unsigned*)(vhc + ((size_t)s_i1[r8][t] << 9));
      float w0 = s_w0[r8][t], w1 = s_w1[r8][t];
      ax += w0 * bf2f((unsigned short)g0) + w1 * bf2f((unsigned short)g1);
      ay += w0 * bf2f((unsigned short)(g0 >> 16)) + w1 * bf2f((unsigned short)(g1 >> 16));
    }
    unsigned packed = (unsigned)f2bf(ax) | ((unsigned)f2bf(ay) << 16);
    *(unsigned*)(attn + (size_t)row2 * 512 + h * 64 + c) = packed;
  }
}

// ---------------- host launcher ----------------
extern "C" void kernel_launch(void* const* d_in, const int* in_sizes, int n_in,
                              void* d_out, int out_size, void* d_ws, size_t ws_size,
                              hipStream_t stream) {
  (void)in_sizes; (void)n_in; (void)out_size; (void)ws_size;
  const float* query = (const float*)d_in[0];
  // d_in[1] = key_in : unused by the reference
  const float* value = (const float*)d_in[2];
  const float* W_v   = (const float*)d_in[3];
  const float* b_v   = (const float*)d_in[4];
  const float* W_off = (const float*)d_in[5];
  const float* b_off = (const float*)d_in[6];
  const float* W_aw  = (const float*)d_in[7];
  const float* b_aw  = (const float*)d_in[8];
  const float* W_out = (const float*)d_in[9];
  const float* b_out = (const float*)d_in[10];
  float* out = (float*)d_out;

  char* ws = (char*)d_ws;
  const size_t MB = 1ull << 20;
  unsigned short* v_bf = (unsigned short*)(ws);                  // 16 MB (v projection, bf16)
  unsigned short* attn = (unsigned short*)(ws + 16 * MB);        // 16 MB
  float* offP          = (float*)(ws + 32 * MB);                 // 2 x 6 MB offaw partials
  unsigned short* Wv_t = (unsigned short*)(ws + 48 * MB);        // 0.5 MB
  unsigned short* Wo_t = (unsigned short*)(ws + 48 * MB + 524288);
  unsigned short* Bhi  = (unsigned short*)(ws + 49 * MB);        // 96 KB
  unsigned short* Blo  = (unsigned short*)(ws + 49 * MB + 98304);
  float* bcat          = (float*)(ws + 49 * MB + 196608);

  // K0: weight prep (tiny)
  prep_w<<<2241, 256, 0, stream>>>(W_v, W_out, W_off, W_aw, b_off, b_aw,
                                   Wv_t, Wo_t, Bhi, Blo, bcat);
  // K1: v = value@W_v + b_v (fp32 A, bf16 out)  ||  offaw split-bf16
  mega_k1<<<2560, 256, 0, stream>>>(value, Wv_t, b_v, v_bf, query, Bhi, Blo, bcat, offP);
  // K2: softmax + grid-sample gather -> attn (bf16)
  sample_kernel<<<2048, 256, 0, stream>>>(offP, v_bf, attn);
  // K3: out = attn @ W_out + b_out (fp32 out)
  gemm2_k<<<2048, 256, 0, stream>>>(attn, Wo_t, b_out, out);
}

// Round 6
// 192.321 us; speedup vs baseline: 1.1492x; 1.1492x over previous
//
#include <hip/hip_runtime.h>
#include <stdint.h>

// Problem: B=8, L=2048, D=512, H=8, P=4, C=64.  M = B*L = 16384.
#define PSZF (16384 * 96)   // elements per offaw partial buffer (split-K half)

using short8  = __attribute__((ext_vector_type(8))) short;
using floatx4 = __attribute__((ext_vector_type(4))) float;

__device__ __forceinline__ unsigned short f2bf(float f) {  // RNE
  union { float f; unsigned u; } v; v.f = f;
  unsigned r = v.u + 0x7fffu + ((v.u >> 16) & 1u);
  return (unsigned short)(r >> 16);
}
__device__ __forceinline__ float bf2f(unsigned short u) {
  union { unsigned u; float f; } v; v.u = ((unsigned)u) << 16; return v.f;
}

__device__ __forceinline__ void load_lds16(const void* g, void* l) {
  __builtin_amdgcn_global_load_lds(
      (const __attribute__((address_space(1))) unsigned int*)g,
      (__attribute__((address_space(3))) unsigned int*)l, 16, 0, 0);
}

__device__ __forceinline__ void store_val(float* p, float v) { *p = v; }
__device__ __forceinline__ void store_val(unsigned short* p, float v) { *p = f2bf(v); }

// ---------------- K0: all conversions / weight prep in one launch ----------------
// [0, 2097152)   : value float4 -> bf16 ushort4
// [.., +262144)  : W_v^T bf16      [.., +262144): W_out^T bf16
// [.., +49152)   : Bhi/Blo split-bf16 of [W_off|W_aw]^T (layout [96][512])
// [.., +96)      : bcat
__global__ __launch_bounds__(256) void prep_all(const float* __restrict__ value,
                                                const float* __restrict__ W_v,
                                                const float* __restrict__ W_out,
                                                const float* __restrict__ Woff,
                                                const float* __restrict__ Waw,
                                                const float* __restrict__ boff,
                                                const float* __restrict__ baw,
                                                unsigned short* __restrict__ val_bf,
                                                unsigned short* __restrict__ Wv_t,
                                                unsigned short* __restrict__ Wo_t,
                                                unsigned short* __restrict__ Bhi,
                                                unsigned short* __restrict__ Blo,
                                                float* __restrict__ bcat) {
  int idx = blockIdx.x * 256 + threadIdx.x;
  if (idx < 2097152) {
    float4 v = ((const float4*)value)[idx];
    ushort4 o;
    o.x = f2bf(v.x); o.y = f2bf(v.y); o.z = f2bf(v.z); o.w = f2bf(v.w);
    ((ushort4*)val_bf)[idx] = o;
    return;
  }
  int t = idx - 2097152;
  if (t < 262144) {
    int n = t >> 9, k = t & 511;
    Wv_t[t] = f2bf(W_v[(k << 9) + n]);
    return;
  }
  t -= 262144;
  if (t < 262144) {
    int n = t >> 9, k = t & 511;
    Wo_t[t] = f2bf(W_out[(k << 9) + n]);
    return;
  }
  t -= 262144;
  if (t < 49152) {
    int n = t >> 9, k = t & 511;
    float w = (n < 64) ? Woff[(k << 6) + n] : Waw[(k << 5) + (n - 64)];
    unsigned short hi = f2bf(w);
    Bhi[t] = hi;
    Blo[t] = f2bf(w - bf2f(hi));
    return;
  }
  t -= 49152;
  if (t < 96) bcat[t] = (t < 64) ? boff[t] : baw[t - 64];
}

// ---------------- 128x128-tile bf16 MFMA GEMM body, BK=64 -------------------------
// BK=64 staged as TWO side-by-side BK=32 chunks (keeps the verified conflict-free
// [128][32] LDS layout; padding would break global_load_lds lane ordering).
// Halves barrier count vs round-4 (8 iters x 32 MFMA): the ~900-cyc HBM drain per
// barrier was the 80%-stall driver at MfmaUtil=10%.
template <typename OutT>
__device__ __forceinline__ void gemm_body64(unsigned char* smem,
                                            const unsigned short* __restrict__ A,
                                            const unsigned short* __restrict__ Bt,
                                            const float* __restrict__ bias,
                                            OutT* __restrict__ C, int bx, int by) {
  unsigned short* lA = (unsigned short*)smem;            // 2 chunks x 8 KB
  unsigned short* lB = (unsigned short*)(smem + 16384);  // 2 chunks x 8 KB
  int tid  = threadIdx.x;
  int lane = tid & 63, wv = tid >> 6;
  int wm = wv & 1, wn = wv >> 1;
  int lrow = lane & 15, quad = lane >> 4;
  int rowBlk = by * 128, colBlk = bx * 128;

  const unsigned short* Ab = A + (size_t)rowBlk * 512;
  const unsigned short* Bb = Bt + (size_t)colBlk * 512;
  int r0 = tid >> 2;            // 0..63
  int c0 = (tid & 3) << 3;      // 0,8,16,24

  floatx4 acc[4][4];
#pragma unroll
  for (int i = 0; i < 4; i++)
#pragma unroll
    for (int j = 0; j < 4; j++) acc[i][j] = (floatx4){0.f, 0.f, 0.f, 0.f};

  for (int k0 = 0; k0 < 512; k0 += 64) {
    // chunk 0: cols [k0, k0+32)
    load_lds16(Ab + (size_t)r0 * 512 + k0 + c0,             lA + tid * 8);
    load_lds16(Ab + (size_t)(r0 + 64) * 512 + k0 + c0,      lA + 2048 + tid * 8);
    load_lds16(Bb + (size_t)r0 * 512 + k0 + c0,             lB + tid * 8);
    load_lds16(Bb + (size_t)(r0 + 64) * 512 + k0 + c0,      lB + 2048 + tid * 8);
    // chunk 1: cols [k0+32, k0+64)
    load_lds16(Ab + (size_t)r0 * 512 + k0 + 32 + c0,        lA + 4096 + tid * 8);
    load_lds16(Ab + (size_t)(r0 + 64) * 512 + k0 + 32 + c0, lA + 6144 + tid * 8);
    load_lds16(Bb + (size_t)r0 * 512 + k0 + 32 + c0,        lB + 4096 + tid * 8);
    load_lds16(Bb + (size_t)(r0 + 64) * 512 + k0 + 32 + c0, lB + 6144 + tid * 8);
    __syncthreads();

#pragma unroll
    for (int kc = 0; kc < 2; kc++) {
      short8 a[4], b[4];
#pragma unroll
      for (int mi = 0; mi < 4; mi++)
        a[mi] = *(const short8*)&lA[kc * 4096 + (wm * 64 + mi * 16 + lrow) * 32 + quad * 8];
#pragma unroll
      for (int ni = 0; ni < 4; ni++)
        b[ni] = *(const short8*)&lB[kc * 4096 + (wn * 64 + ni * 16 + lrow) * 32 + quad * 8];
#pragma unroll
      for (int mi = 0; mi < 4; mi++)
#pragma unroll
        for (int ni = 0; ni < 4; ni++)
          acc[mi][ni] = __builtin_amdgcn_mfma_f32_16x16x32_bf16(a[mi], b[ni], acc[mi][ni], 0, 0, 0);
    }
    __syncthreads();
  }

  // C/D layout: col = lane&15, row = quad*4 + reg   [verified m89/m91]
#pragma unroll
  for (int ni = 0; ni < 4; ni++) {
    int col = colBlk + wn * 64 + ni * 16 + lrow;
    float bv = bias[col];
#pragma unroll
    for (int mi = 0; mi < 4; mi++) {
      int row = rowBlk + wm * 64 + mi * 16 + quad * 4;
#pragma unroll
      for (int r = 0; r < 4; r++)
        store_val(&C[(size_t)(row + r) * 512 + col], acc[mi][ni][r] + bv);
    }
  }
}

// XCD-aware swizzle for 512-block GEMMs: x = bid&7 (XCD under %8 round-robin),
// s = bid>>3; same-XCD blocks share a 16-row-tile band of A -> per-XCD L2 holds
// a 2 MB A-slice + 0.5 MB B (round-5 evidence: tile shrink -> FETCH 50->148 MB;
// this goes the other way: group for reuse).
__device__ __forceinline__ void swz512(int bid, int& bx, int& by) {
  int x = bid & 7, s = bid >> 3;
  by = (x << 4) | (s >> 2);
  bx = s & 3;
}

// ---------------- offaw body: split-bf16 3-product MFMA (round-4 proven) ----------
__device__ __forceinline__ void offaw_body(unsigned char* smem,
                                           const float* __restrict__ Q,
                                           const unsigned short* __restrict__ Bhi,
                                           const unsigned short* __restrict__ Blo,
                                           const float* __restrict__ bcat,
                                           float* __restrict__ P, int bid) {
  unsigned short* lAhi = (unsigned short*)smem;            // 64*32 = 4 KB
  unsigned short* lAlo = (unsigned short*)(smem + 4096);   // 4 KB
  unsigned short* lBhi = (unsigned short*)(smem + 8192);   // 96*32 = 6 KB
  unsigned short* lBlo = (unsigned short*)(smem + 14336);  // 6 KB
  int khalf = bid >> 8, row0 = (bid & 255) * 64, kbase = khalf << 8;
  int tid = threadIdx.x, lane = tid & 63, wv = tid >> 6;
  int wm = wv & 1, wn = wv >> 1, lrow = lane & 15, quad = lane >> 4;

  int ar = tid >> 2, ac = (tid & 3) << 3;
  const float* qp = Q + (size_t)(row0 + ar) * 512 + kbase + ac;

  floatx4 acc[2][3];
#pragma unroll
  for (int i = 0; i < 2; i++)
#pragma unroll
    for (int j = 0; j < 3; j++) acc[i][j] = (floatx4){0.f, 0.f, 0.f, 0.f};

  for (int k0 = 0; k0 < 256; k0 += 32) {
    float4 v0 = *(const float4*)(qp + k0);
    float4 v1 = *(const float4*)(qp + k0 + 4);
    float vv[8] = {v0.x, v0.y, v0.z, v0.w, v1.x, v1.y, v1.z, v1.w};
    short8 h8, l8;
#pragma unroll
    for (int e = 0; e < 8; e++) {
      union { float f; unsigned u; } t; t.f = vv[e];
      unsigned r = t.u + 0x7fffu + ((t.u >> 16) & 1u);
      h8[e] = (short)(r >> 16);
      union { unsigned u; float f; } hf; hf.u = r & 0xffff0000u;
      union { float f; unsigned u; } rb; rb.f = vv[e] - hf.f;
      l8[e] = (short)(rb.u >> 16);
    }
    *(short8*)&lAhi[tid * 8] = h8;
    *(short8*)&lAlo[tid * 8] = l8;
#pragma unroll
    for (int j = 0; j < 3; j++) {
      int widx = wv + (j << 2);                        // 0..11, wave-uniform
      const unsigned short* src = (widx < 6) ? Bhi : Blo;
      unsigned short* dst = (widx < 6) ? lBhi : lBlo;
      int c = (((widx < 6) ? widx : widx - 6) << 6) + lane;  // 0..383
      int n = c >> 2, cc = (c & 3) << 3;
      load_lds16(src + (size_t)n * 512 + kbase + k0 + cc, dst + c * 8);
    }
    __syncthreads();

    short8 ah[2], al[2], bh[3], bl[3];
#pragma unroll
    for (int mi = 0; mi < 2; mi++) {
      int r = (wm * 32 + mi * 16 + lrow) * 32 + quad * 8;
      ah[mi] = *(const short8*)&lAhi[r];
      al[mi] = *(const short8*)&lAlo[r];
    }
#pragma unroll
    for (int ni = 0; ni < 3; ni++) {
      int r = (wn * 48 + ni * 16 + lrow) * 32 + quad * 8;
      bh[ni] = *(const short8*)&lBhi[r];
      bl[ni] = *(const short8*)&lBlo[r];
    }
#pragma unroll
    for (int mi = 0; mi < 2; mi++)
#pragma unroll
      for (int ni = 0; ni < 3; ni++) {
        acc[mi][ni] = __builtin_amdgcn_mfma_f32_16x16x32_bf16(ah[mi], bh[ni], acc[mi][ni], 0, 0, 0);
        acc[mi][ni] = __builtin_amdgcn_mfma_f32_16x16x32_bf16(ah[mi], bl[ni], acc[mi][ni], 0, 0, 0);
        acc[mi][ni] = __builtin_amdgcn_mfma_f32_16x16x32_bf16(al[mi], bh[ni], acc[mi][ni], 0, 0, 0);
      }
    __syncthreads();
  }

  float* out = P + (size_t)khalf * PSZF;
#pragma unroll
  for (int ni = 0; ni < 3; ni++) {
    int col = wn * 48 + ni * 16 + lrow;
    float bv = (khalf == 0) ? bcat[col] : 0.0f;
#pragma unroll
    for (int mi = 0; mi < 2; mi++) {
      int row = row0 + wm * 32 + mi * 16 + quad * 4;
#pragma unroll
      for (int r = 0; r < 4; r++)
        out[(size_t)(row + r) * 96 + col] = acc[mi][ni][r] + bv;
    }
  }
}

// ---------------- K1: gemm1 (512 blocks, swizzled) + offaw (512 blocks) -----------
__global__ __launch_bounds__(256) void mega_k1(const unsigned short* __restrict__ val_bf,
                                               const unsigned short* __restrict__ Wv_t,
                                               const float* __restrict__ b_v,
                                               unsigned short* __restrict__ v_bf,
                                               const float* __restrict__ query,
                                               const unsigned short* __restrict__ Bhi,
                                               const unsigned short* __restrict__ Blo,
                                               const float* __restrict__ bcat,
                                               float* __restrict__ offP) {
  __shared__ __align__(16) unsigned char smem[32768];
  int bid = blockIdx.x;
  if (bid < 512) {
    int bx, by; swz512(bid, bx, by);
    gemm_body64<unsigned short>(smem, val_bf, Wv_t, b_v, v_bf, bx, by);
  } else {
    offaw_body(smem, query, Bhi, Blo, bcat, offP, bid - 512);
  }
}

// ---------------- K3: out = attn @ W_out + b_out (512 blocks, swizzled) -----------
__global__ __launch_bounds__(256) void gemm2_k(const unsigned short* __restrict__ A,
                                               const unsigned short* __restrict__ Bt,
                                               const float* __restrict__ bias,
                                               float* __restrict__ C) {
  __shared__ __align__(16) unsigned char smem[32768];
  int bx, by; swz512(blockIdx.x, bx, by);
  gemm_body64<float>(smem, A, Bt, bias, C, bx, by);
}

// ---------------- K2: fused softmax + 1-D grid-sample gather ----------------------
// 8 rows per block; all 256 threads active in setup (thread = (row, h*4+p)).
// iy0 == 0 always (iy in [0,0.5]) so ywt = 1 - 0.5*loc_y.
__global__ __launch_bounds__(256) void sample_kernel(const float* __restrict__ P,
                                                     const unsigned short* __restrict__ v,
                                                     unsigned short* __restrict__ attn) {
  int tid = threadIdx.x;
  int rr = tid >> 5, hp = tid & 31;
  int row = blockIdx.x * 8 + rr;
  int l = row & 2047;
  __shared__ float s_w0[8][32], s_w1[8][32];
  __shared__ int s_i0[8][32], s_i1[8][32];
  {
    int base = row * 96;
    float lg = P[base + 64 + hp] + P[PSZF + base + 64 + hp];
    float mx = fmaxf(lg, __shfl_xor(lg, 1));
    mx = fmaxf(mx, __shfl_xor(mx, 2));
    float e = __expf(lg - mx);
    float s = e + __shfl_xor(e, 1);
    s = s + __shfl_xor(s, 2);
    float aw = e / s;

    float ox = P[base + 2 * hp] + P[PSZF + base + 2 * hp];
    float oy = P[base + 2 * hp + 1] + P[PSZF + base + 2 * hp + 1];
    float refy = (float)l * (1.0f / 2047.0f);
    float lx = fminf(fmaxf(ox, 0.0f), 1.0f);
    float ly = fminf(fmaxf(oy + refy, 0.0f), 1.0f);
    float ix = ((lx + 1.0f) * 2048.0f - 1.0f) * 0.5f;
    float ywt = 1.0f - ly * 0.5f;
    float ix0 = floorf(ix);
    float fx = ix - ix0;
    int i0 = (int)ix0;
    int i1 = i0 + 1;
    s_w0[rr][hp] = aw * ywt * (1.0f - fx);
    s_w1[rr][hp] = (i1 < 2048) ? (aw * ywt * fx) : 0.0f;
    s_i0[rr][hp] = i0;
    s_i1[rr][hp] = (i1 < 2048) ? i1 : 2047;
  }
  __syncthreads();

  int b = (blockIdx.x * 8) >> 11;                 // 8 rows never cross a batch
  int h = tid >> 5, c = (tid & 31) << 1;
  const unsigned short* vhc = v + ((size_t)(b << 11)) * 512 + h * 64 + c;
#pragma unroll
  for (int r8 = 0; r8 < 8; r8++) {
    int row2 = blockIdx.x * 8 + r8;
    float ax = 0.0f, ay = 0.0f;
#pragma unroll
    for (int p = 0; p < 4; p++) {
      int t = (h << 2) + p;
      unsigned g0 = *(const unsigned*)(vhc + ((size_t)s_i0[r8][t] << 9));
      unsigned g1 = *(const unsigned*)(vhc + ((size_t)s_i1[r8][t] << 9));
      float w0 = s_w0[r8][t], w1 = s_w1[r8][t];
      ax += w0 * bf2f((unsigned short)g0) + w1 * bf2f((unsigned short)g1);
      ay += w0 * bf2f((unsigned short)(g0 >> 16)) + w1 * bf2f((unsigned short)(g1 >> 16));
    }
    unsigned packed = (unsigned)f2bf(ax) | ((unsigned)f2bf(ay) << 16);
    *(unsigned*)(attn + (size_t)row2 * 512 + h * 64 + c) = packed;
  }
}

// ---------------- host launcher ----------------
extern "C" void kernel_launch(void* const* d_in, const int* in_sizes, int n_in,
                              void* d_out, int out_size, void* d_ws, size_t ws_size,
                              hipStream_t stream) {
  (void)in_sizes; (void)n_in; (void)out_size; (void)ws_size;
  const float* query = (const float*)d_in[0];
  // d_in[1] = key_in : unused by the reference
  const float* value = (const float*)d_in[2];
  const float* W_v   = (const float*)d_in[3];
  const float* b_v   = (const float*)d_in[4];
  const float* W_off = (const float*)d_in[5];
  const float* b_off = (const float*)d_in[6];
  const float* W_aw  = (const float*)d_in[7];
  const float* b_aw  = (const float*)d_in[8];
  const float* W_out = (const float*)d_in[9];
  const float* b_out = (const float*)d_in[10];
  float* out = (float*)d_out;

  char* ws = (char*)d_ws;
  const size_t MB = 1ull << 20;
  unsigned short* val_bf = (unsigned short*)(ws);                  // 16 MB (value bf16)
  unsigned short* attn   = val_bf;                                 // alias: value dead after K1
  unsigned short* v_bf   = (unsigned short*)(ws + 16 * MB);        // 16 MB (v projection)
  float* offP            = (float*)(ws + 32 * MB);                 // 2 x 6 MB offaw partials
  unsigned short* Wv_t   = (unsigned short*)(ws + 48 * MB);        // 0.5 MB
  unsigned short* Wo_t   = (unsigned short*)(ws + 48 * MB + 524288);
  unsigned short* Bhi    = (unsigned short*)(ws + 49 * MB);        // 96 KB
  unsigned short* Blo    = (unsigned short*)(ws + 49 * MB + 98304);
  float* bcat            = (float*)(ws + 49 * MB + 196608);

  // K0: value conv + weight prep
  prep_all<<<10433, 256, 0, stream>>>(value, W_v, W_out, W_off, W_aw, b_off, b_aw,
                                      val_bf, Wv_t, Wo_t, Bhi, Blo, bcat);
  // K1: v = value@W_v + b_v (bf16 out)  ||  offaw split-bf16
  mega_k1<<<1024, 256, 0, stream>>>(val_bf, Wv_t, b_v, v_bf, query, Bhi, Blo, bcat, offP);
  // K2: softmax + grid-sample gather -> attn (bf16)
  sample_kernel<<<2048, 256, 0, stream>>>(offP, v_bf, attn);
  // K3: out = attn @ W_out + b_out (fp32 out)
  gemm2_k<<<512, 256, 0, stream>>>(attn, Wo_t, b_out, out);
}